// Round 3
// baseline (1180.312 us; speedup 1.0000x reference)
//
#include <hip/hip_runtime.h>
#include <hip/hip_bf16.h>

#define NB 4096
#define NT 50
#define NH 128
#define NINT 4
#define ROWS 32  // batch rows per block

typedef float f32x4 __attribute__((ext_vector_type(4)));
typedef __bf16 bf16x8 __attribute__((ext_vector_type(8)));
typedef short short8 __attribute__((ext_vector_type(8)));

__device__ __forceinline__ float frcp(float x) { return __builtin_amdgcn_rcpf(x); }

__device__ __forceinline__ unsigned short bfbits(float f) {
  __bf16 b = (__bf16)f;  // native RTNE cvt; compiler packs pairs to v_cvt_pk_bf16_f32
  return __builtin_bit_cast(unsigned short, b);
}

// Grid: 512 blocks = NINT(4) * (NB/32)(128).  Block: 512 threads = 8 waves.
// Each block owns one interest and 32 batch rows; 2 blocks co-resident per CU.
__global__ __launch_bounds__(512, 4)
void gru_fused(const int* __restrict__ inputs, const float* __restrict__ emb,
               const float* __restrict__ w_int, const float* __restrict__ w_ih,
               const float* __restrict__ w_hh, const float* __restrict__ b_ih,
               const float* __restrict__ b_hh, const float* __restrict__ h0,
               float* __restrict__ out) {
  __shared__ unsigned short xs[2][ROWS * NH];  // x tile, bf16, XOR-swizzled
  __shared__ unsigned short hs[2][ROWS * NH];  // h tile, bf16, XOR-swizzled
  __shared__ float gall[NT * ROWS];            // gate g for ALL timesteps (prologue)
  __shared__ int idxs[NT * ROWS];              // [t][r] token ids
  __shared__ float wintl[NINT * NH];           // w_interest (prologue only)

  const int tid = threadIdx.x;
  const int bx = blockIdx.x;
  const int I = bx >> 7;            // interest 0..3
  const int R0 = (bx & 127) * ROWS; // first batch row
  const int w = tid >> 6;           // wave 0..7
  const int lane = tid & 63;
  const int l15 = lane & 15;
  const int l4 = lane >> 4;
  const int col = w * 16 + l15;     // this lane's output column (0..127)

  // stage mapping: 16 threads per row, 8 elems each
  const int sr = tid >> 4;   // row 0..31
  const int sseg = tid & 15; // segment (8 floats)

  // ---- one-time loads: token indices + w_interest ----
  for (int e = tid; e < NT * ROWS; e += 512) {
    int t = e >> 5, r = e & (ROWS - 1);
    idxs[e] = inputs[(size_t)(R0 + r) * NT + t];
  }
  if (tid < NINT * NH) wintl[tid] = w_int[tid];
  __syncthreads();

  // ---- precompute interest gate g[t][r] for ALL timesteps (VALU, parallel) ----
  const float4* wld = (const float4*)wintl;
  #pragma unroll
  for (int p = 0; p < 4; ++p) {
    int e = tid + p * 512;
    if (e < NT * ROWS) {
      int t = e >> 5, r = e & (ROWS - 1);
      const float4* xr = (const float4*)(emb + (size_t)idxs[e] * NH);
      float d0 = 0.f, d1 = 0.f, d2 = 0.f, d3 = 0.f;
      for (int k = 0; k < 32; ++k) {
        float4 xv = xr[k];
        float4 w0 = wld[k], w1 = wld[32 + k], w2 = wld[64 + k], w3 = wld[96 + k];
        d0 += xv.x * w0.x + xv.y * w0.y + xv.z * w0.z + xv.w * w0.w;
        d1 += xv.x * w1.x + xv.y * w1.y + xv.z * w1.z + xv.w * w1.w;
        d2 += xv.x * w2.x + xv.y * w2.y + xv.z * w2.z + xv.w * w2.w;
        d3 += xv.x * w3.x + xv.y * w3.y + xv.z * w3.z + xv.w * w3.w;
      }
      float sa = d0 * 10.f, sb = d1 * 10.f, sc = d2 * 10.f, sd = d3 * 10.f;
      float mx = fmaxf(fmaxf(sa, sb), fmaxf(sc, sd));
      float ea = __expf(sa - mx), eb = __expf(sb - mx), ec = __expf(sc - mx),
            ed = __expf(sd - mx);
      float sel = (I == 0) ? ea : (I == 1) ? eb : (I == 2) ? ec : ed;
      gall[e] = sel * frcp(ea + eb + ec + ed);
    }
  }

  // ---- persistent weight fragments in registers (bf16) ----
  // B-operand of 16x16x32: lane holds col=(lane&15), k = (lane>>4)*8 + 0..7
  bf16x8 wih[3][4], whh[3][4];
  float bih[3], bhh[3];
  #pragma unroll
  for (int g = 0; g < 3; ++g) {
    int oc = g * NH + col;
    bih[g] = b_ih[I * 384 + oc];
    bhh[g] = b_hh[I * 384 + oc];
    #pragma unroll
    for (int kk = 0; kk < 4; ++kk) {
      int k0 = kk * 32 + l4 * 8;
      const float* pi = w_ih + ((size_t)(I * 384 + oc) * NH + k0);
      const float* ph = w_hh + ((size_t)(I * 384 + oc) * NH + k0);
      bf16x8 si, sh;
      #pragma unroll
      for (int e = 0; e < 8; ++e) {
        si[e] = (__bf16)pi[e];
        sh[e] = (__bf16)ph[e];
      }
      wih[g][kk] = si;
      whh[g][kk] = sh;
    }
  }

  // ---- h0 master (fp32 regs) + initial bf16 LDS copy ----
  // C/D layout: col = lane&15, row = (lane>>4)*4 + reg
  float hm[2][4];
  #pragma unroll
  for (int m = 0; m < 2; ++m) {
    #pragma unroll
    for (int j = 0; j < 4; ++j) {
      int row = m * 16 + l4 * 4 + j;
      float v = h0[((size_t)I * NB + R0 + row) * NH + col];
      hm[m][j] = v;
      hs[0][(row * NH + col) ^ ((row & 7) << 3)] = bfbits(v);
    }
  }

  // ---- stage x(0) ----
  {
    const float4* src = (const float4*)(emb + (size_t)idxs[0 * ROWS + sr] * NH) + sseg * 2;
    float4 a = src[0], b = src[1];
    bf16x8 v;
    v[0] = (__bf16)a.x; v[1] = (__bf16)a.y; v[2] = (__bf16)a.z; v[3] = (__bf16)a.w;
    v[4] = (__bf16)b.x; v[5] = (__bf16)b.y; v[6] = (__bf16)b.z; v[7] = (__bf16)b.w;
    int base = sr * NH + sseg * 8;
    *(short8*)&xs[0][base ^ ((sr & 7) << 3)] = __builtin_bit_cast(short8, v);
  }
  __syncthreads();

  // ---- main recurrence ----
  for (int t = 0; t < NT; ++t) {
    const int cur = t & 1, nxt = cur ^ 1;

    // prefetch x(t+1) into regs (latency hides under MFMAs)
    float4 pa, pb;
    const bool pf = (t + 1 < NT);
    if (pf) {
      const float4* src =
          (const float4*)(emb + (size_t)idxs[(t + 1) * ROWS + sr] * NH) + sseg * 2;
      pa = src[0];
      pb = src[1];
    }

    const unsigned short* hsc = hs[cur];
    const unsigned short* xsc = xs[cur];
    unsigned short* hsn = hs[nxt];

    #pragma unroll
    for (int m = 0; m < 2; ++m) {
      f32x4 agi[3], agh[3];
      #pragma unroll
      for (int g = 0; g < 3; ++g) {
        agi[g] = f32x4{bih[g], bih[g], bih[g], bih[g]};
        agh[g] = f32x4{bhh[g], bhh[g], bhh[g], bhh[g]};
      }
      int arow = m * 16 + l15;
      int alin = arow * NH + l4 * 8;  // bits 3-4
      int sw = (arow & 7) << 3;       // bits 3-5
      #pragma unroll
      for (int kk = 0; kk < 4; ++kk) {
        int e = (alin + kk * 32) ^ sw;  // kk*32: bits 5-6, add carry-free; XOR full index
        bf16x8 ah = __builtin_bit_cast(bf16x8, *(const short8*)&hsc[e]);
        bf16x8 ax = __builtin_bit_cast(bf16x8, *(const short8*)&xsc[e]);
        #pragma unroll
        for (int g = 0; g < 3; ++g) {
          agh[g] = __builtin_amdgcn_mfma_f32_16x16x32_bf16(ah, whh[g][kk], agh[g], 0, 0, 0);
          agi[g] = __builtin_amdgcn_mfma_f32_16x16x32_bf16(ax, wih[g][kk], agi[g], 0, 0, 0);
        }
      }
      #pragma unroll
      for (int j = 0; j < 4; ++j) {
        int row = m * 16 + l4 * 4 + j;
        float gv = gall[t * ROWS + row];
        float rg = frcp(1.0f + __expf(-(agi[0][j] + agh[0][j])));
        float ig = frcp(1.0f + __expf(-(agi[1][j] + agh[1][j])));
        float na = agi[2][j] + rg * agh[2][j];
        float ng = 2.0f * frcp(1.0f + __expf(-2.0f * na)) - 1.0f;
        float c = (gv > 0.01f) ? gv * ig : 0.0f;
        float hy = hm[m][j] + c * (ng - hm[m][j]);
        hm[m][j] = hy;
        hsn[(row * NH + col) ^ ((row & 7) << 3)] = bfbits(hy);
      }
    }

    if (pf) {
      bf16x8 v;
      v[0] = (__bf16)pa.x; v[1] = (__bf16)pa.y; v[2] = (__bf16)pa.z; v[3] = (__bf16)pa.w;
      v[4] = (__bf16)pb.x; v[5] = (__bf16)pb.y; v[6] = (__bf16)pb.z; v[7] = (__bf16)pb.w;
      int base = sr * NH + sseg * 8;
      *(short8*)&xs[nxt][base ^ ((sr & 7) << 3)] = __builtin_bit_cast(short8, v);
    }
    __syncthreads();
  }

  // ---- epilogue: out[b][I][h] ----
  #pragma unroll
  for (int m = 0; m < 2; ++m) {
    #pragma unroll
    for (int j = 0; j < 4; ++j) {
      int row = m * 16 + l4 * 4 + j;
      out[(size_t)(R0 + row) * (NINT * NH) + I * NH + col] = hm[m][j];
    }
  }
}

extern "C" void kernel_launch(void* const* d_in, const int* in_sizes, int n_in,
                              void* d_out, int out_size, void* d_ws, size_t ws_size,
                              hipStream_t stream) {
  const int* inputs = (const int*)d_in[0];
  const float* emb = (const float*)d_in[1];
  const float* w_int = (const float*)d_in[2];
  const float* w_ih = (const float*)d_in[3];
  const float* w_hh = (const float*)d_in[4];
  const float* b_ih = (const float*)d_in[5];
  const float* b_hh = (const float*)d_in[6];
  const float* h0 = (const float*)d_in[7];
  float* out = (float*)d_out;

  dim3 grid(NINT * (NB / ROWS));  // 512 blocks -> 2 per CU
  dim3 block(512);
  gru_fused<<<grid, block, 0, stream>>>(inputs, emb, w_int, w_ih, w_hh, b_ih,
                                        b_hh, h0, out);
}

// Round 4
// 1071.984 us; speedup vs baseline: 1.1011x; 1.1011x over previous
//
#include <hip/hip_runtime.h>
#include <hip/hip_bf16.h>

#define NB 4096
#define NT 50
#define NH 128
#define NINT 4
#define ROWS 32  // batch rows per block

typedef float f32x4 __attribute__((ext_vector_type(4)));
typedef __bf16 bf16x8 __attribute__((ext_vector_type(8)));
typedef short short8 __attribute__((ext_vector_type(8)));

__device__ __forceinline__ float frcp(float x) { return __builtin_amdgcn_rcpf(x); }

__device__ __forceinline__ unsigned short bfbits(float f) {
  __bf16 b = (__bf16)f;  // native RTNE cvt; pairs pack to v_cvt_pk_bf16_f32
  return __builtin_bit_cast(unsigned short, b);
}

// Grid: 512 blocks = NINT(4) * (NB/32)(128).  Block: 512 threads = 8 waves.
// Each block owns one interest and 32 batch rows; 2 blocks co-resident per CU.
__global__ __launch_bounds__(512, 4)
void gru_fused(const int* __restrict__ inputs, const float* __restrict__ emb,
               const float* __restrict__ w_int, const float* __restrict__ w_ih,
               const float* __restrict__ w_hh, const float* __restrict__ b_ih,
               const float* __restrict__ b_hh, const float* __restrict__ h0,
               float* __restrict__ out) {
  __shared__ unsigned short xs[2][ROWS * NH];  // x tile, bf16, XOR-swizzled
  __shared__ unsigned short hs[2][ROWS * NH];  // h tile, bf16, XOR-swizzled
  __shared__ float gall[NT * ROWS];            // gate g for ALL timesteps
  __shared__ int idxs[NT * ROWS];              // [t][r] token ids
  __shared__ float wintl[NINT * NH];           // w_interest (prologue only)

  const int tid = threadIdx.x;
  const int bx = blockIdx.x;
  const int I = bx >> 7;            // interest 0..3
  const int R0 = (bx & 127) * ROWS; // first batch row
  const int w = tid >> 6;           // wave 0..7
  const int lane = tid & 63;
  const int l15 = lane & 15;
  const int l4 = lane >> 4;
  const int col = w * 16 + l15;     // this lane's output column (0..127)

  // stage mapping: 16 threads per row, 8 elems each (coalesced 512B/row)
  const int sr = tid >> 4;   // row 0..31
  const int sseg = tid & 15; // segment (8 floats)

  // ---- one-time loads: token indices + w_interest ----
  for (int e = tid; e < NT * ROWS; e += 512) {
    int t = e >> 5, r = e & (ROWS - 1);
    idxs[e] = inputs[(size_t)(R0 + r) * NT + t];
  }
  wintl[tid] = w_int[tid];  // 512 == NINT*NH
  __syncthreads();

  // ---- precompute interest gate g[t][r] for ALL timesteps, COALESCED ----
  // 16 threads per (t,r) row: 32B/lane contiguous, shuffle-reduce the dots.
  {
    // hoist w_interest fragments to registers (prologue-only live range)
    float4 wA[NINT], wB[NINT];
    #pragma unroll
    for (int i = 0; i < NINT; ++i) {
      const float4* wv = (const float4*)(wintl + i * NH) + sseg * 2;
      wA[i] = wv[0];
      wB[i] = wv[1];
    }
    for (int pass = 0; pass < NT; ++pass) {
      int e = pass * ROWS + sr;  // t = pass, r = sr
      const float4* xr = (const float4*)(emb + (size_t)idxs[e] * NH) + sseg * 2;
      float4 a = xr[0], b = xr[1];
      float d[NINT];
      #pragma unroll
      for (int i = 0; i < NINT; ++i) {
        d[i] = a.x * wA[i].x + a.y * wA[i].y + a.z * wA[i].z + a.w * wA[i].w +
               b.x * wB[i].x + b.y * wB[i].y + b.z * wB[i].z + b.w * wB[i].w;
      }
      #pragma unroll
      for (int off = 1; off < 16; off <<= 1) {
        #pragma unroll
        for (int i = 0; i < NINT; ++i) d[i] += __shfl_xor(d[i], off, 64);
      }
      if (sseg == 0) {
        float sa = d[0] * 10.f, sb = d[1] * 10.f, sc = d[2] * 10.f, sd = d[3] * 10.f;
        float mx = fmaxf(fmaxf(sa, sb), fmaxf(sc, sd));
        float ea = __expf(sa - mx), eb = __expf(sb - mx), ec = __expf(sc - mx),
              ed = __expf(sd - mx);
        float sel = (I == 0) ? ea : (I == 1) ? eb : (I == 2) ? ec : ed;
        gall[e] = sel * frcp(ea + eb + ec + ed);
      }
    }
  }

  // ---- persistent weight fragments in registers (bf16) ----
  // B-operand of 16x16x32: lane holds col=(lane&15), k = (lane>>4)*8 + 0..7
  bf16x8 wih[3][4], whh[3][4];
  float bih[3], bhh[3];
  #pragma unroll
  for (int g = 0; g < 3; ++g) {
    int oc = g * NH + col;
    bih[g] = b_ih[I * 384 + oc];
    bhh[g] = b_hh[I * 384 + oc];
    #pragma unroll
    for (int kk = 0; kk < 4; ++kk) {
      int k0 = kk * 32 + l4 * 8;
      const float* pi = w_ih + ((size_t)(I * 384 + oc) * NH + k0);
      const float* ph = w_hh + ((size_t)(I * 384 + oc) * NH + k0);
      bf16x8 si, sh;
      #pragma unroll
      for (int e = 0; e < 8; ++e) {
        si[e] = (__bf16)pi[e];
        sh[e] = (__bf16)ph[e];
      }
      wih[g][kk] = si;
      whh[g][kk] = sh;
    }
  }

  // ---- h0 master (fp32 regs) + initial bf16 LDS copy ----
  // C/D layout: col = lane&15, row = (lane>>4)*4 + reg
  float hm[2][4];
  #pragma unroll
  for (int m = 0; m < 2; ++m) {
    #pragma unroll
    for (int j = 0; j < 4; ++j) {
      int row = m * 16 + l4 * 4 + j;
      float v = h0[((size_t)I * NB + R0 + row) * NH + col];
      hm[m][j] = v;
      hs[0][(row * NH + col) ^ ((row & 7) << 3)] = bfbits(v);
    }
  }

  // ---- stage x(0) ----
  {
    const float4* src = (const float4*)(emb + (size_t)idxs[0 * ROWS + sr] * NH) + sseg * 2;
    float4 a = src[0], b = src[1];
    bf16x8 v;
    v[0] = (__bf16)a.x; v[1] = (__bf16)a.y; v[2] = (__bf16)a.z; v[3] = (__bf16)a.w;
    v[4] = (__bf16)b.x; v[5] = (__bf16)b.y; v[6] = (__bf16)b.z; v[7] = (__bf16)b.w;
    int base = sr * NH + sseg * 8;
    *(short8*)&xs[0][base ^ ((sr & 7) << 3)] = __builtin_bit_cast(short8, v);
  }
  __syncthreads();

  // ---- main recurrence ----
  for (int t = 0; t < NT; ++t) {
    const int cur = t & 1, nxt = cur ^ 1;

    // prefetch x(t+1) into regs (latency hides under MFMAs)
    float4 pa, pb;
    const bool pf = (t + 1 < NT);
    if (pf) {
      const float4* src =
          (const float4*)(emb + (size_t)idxs[(t + 1) * ROWS + sr] * NH) + sseg * 2;
      pa = src[0];
      pb = src[1];
    }

    const unsigned short* hsc = hs[cur];
    const unsigned short* xsc = xs[cur];
    unsigned short* hsn = hs[nxt];

    #pragma unroll
    for (int m = 0; m < 2; ++m) {
      f32x4 agi[3], agh[3];
      #pragma unroll
      for (int g = 0; g < 3; ++g) {
        agi[g] = f32x4{bih[g], bih[g], bih[g], bih[g]};
        agh[g] = f32x4{bhh[g], bhh[g], bhh[g], bhh[g]};
      }
      int arow = m * 16 + l15;
      int alin = arow * NH + l4 * 8;  // bits 3-4
      int sw = (arow & 7) << 3;       // bits 3-5
      #pragma unroll
      for (int kk = 0; kk < 4; ++kk) {
        int e = (alin + kk * 32) ^ sw;  // kk*32: bits 5-6, carry-free; XOR full index
        bf16x8 ah = __builtin_bit_cast(bf16x8, *(const short8*)&hsc[e]);
        bf16x8 ax = __builtin_bit_cast(bf16x8, *(const short8*)&xsc[e]);
        #pragma unroll
        for (int g = 0; g < 3; ++g) {
          agh[g] = __builtin_amdgcn_mfma_f32_16x16x32_bf16(ah, whh[g][kk], agh[g], 0, 0, 0);
          agi[g] = __builtin_amdgcn_mfma_f32_16x16x32_bf16(ax, wih[g][kk], agi[g], 0, 0, 0);
        }
      }
      #pragma unroll
      for (int j = 0; j < 4; ++j) {
        int row = m * 16 + l4 * 4 + j;
        float gv = gall[t * ROWS + row];
        float rg = frcp(1.0f + __expf(-(agi[0][j] + agh[0][j])));
        float ig = frcp(1.0f + __expf(-(agi[1][j] + agh[1][j])));
        float na = agi[2][j] + rg * agh[2][j];
        float ng = 2.0f * frcp(1.0f + __expf(-2.0f * na)) - 1.0f;
        float c = (gv > 0.01f) ? gv * ig : 0.0f;
        float hy = hm[m][j] + c * (ng - hm[m][j]);
        hm[m][j] = hy;
        hsn[(row * NH + col) ^ ((row & 7) << 3)] = bfbits(hy);
      }
    }

    if (pf) {
      bf16x8 v;
      v[0] = (__bf16)pa.x; v[1] = (__bf16)pa.y; v[2] = (__bf16)pa.z; v[3] = (__bf16)pa.w;
      v[4] = (__bf16)pb.x; v[5] = (__bf16)pb.y; v[6] = (__bf16)pb.z; v[7] = (__bf16)pb.w;
      int base = sr * NH + sseg * 8;
      *(short8*)&xs[nxt][base ^ ((sr & 7) << 3)] = __builtin_bit_cast(short8, v);
    }
    __syncthreads();
  }

  // ---- epilogue: out[b][I][h] ----
  #pragma unroll
  for (int m = 0; m < 2; ++m) {
    #pragma unroll
    for (int j = 0; j < 4; ++j) {
      int row = m * 16 + l4 * 4 + j;
      out[(size_t)(R0 + row) * (NINT * NH) + I * NH + col] = hm[m][j];
    }
  }
}

extern "C" void kernel_launch(void* const* d_in, const int* in_sizes, int n_in,
                              void* d_out, int out_size, void* d_ws, size_t ws_size,
                              hipStream_t stream) {
  const int* inputs = (const int*)d_in[0];
  const float* emb = (const float*)d_in[1];
  const float* w_int = (const float*)d_in[2];
  const float* w_ih = (const float*)d_in[3];
  const float* w_hh = (const float*)d_in[4];
  const float* b_ih = (const float*)d_in[5];
  const float* b_hh = (const float*)d_in[6];
  const float* h0 = (const float*)d_in[7];
  float* out = (float*)d_out;

  dim3 grid(NINT * (NB / ROWS));  // 512 blocks -> 2 per CU
  dim3 block(512);
  gru_fused<<<grid, block, 0, stream>>>(inputs, emb, w_int, w_ih, w_hh, b_ih,
                                        b_hh, h0, out);
}

// Round 5
// 759.987 us; speedup vs baseline: 1.5531x; 1.4105x over previous
//
#include <hip/hip_runtime.h>
#include <hip/hip_bf16.h>

#define NB 4096
#define NT 50
#define NH 128
#define NINT 4
#define ROWS 64    // batch rows per block
#define XSTR 392   // gi-exchange row stride in bf16 elems (384 + 8 pad)

typedef float f32x4 __attribute__((ext_vector_type(4)));
typedef __bf16 bf16x8 __attribute__((ext_vector_type(8)));
typedef short short8 __attribute__((ext_vector_type(8)));

__device__ __forceinline__ float frcp(float x) { return __builtin_amdgcn_rcpf(x); }

__device__ __forceinline__ unsigned short bfbits(float f) {
  __bf16 b = (__bf16)f;
  return __builtin_bit_cast(unsigned short, b);
}
__device__ __forceinline__ float bf2f(unsigned short u) {
  return __uint_as_float((unsigned)u << 16);
}
__device__ __forceinline__ float sigm(float x) {
  return frcp(1.0f + __expf(-x));
}
__device__ __forceinline__ float tanh_(float x) {
  return 2.0f * frcp(1.0f + __expf(-2.0f * x)) - 1.0f;
}

// Grid: 256 blocks = NINT(4) * (NB/64).  Block: 1024 threads = 16 waves, 1/CU.
// Crew split: waves 0-7 (X-crew) hold w_ih only, compute gi = x@Wih^T.
//             waves 8-15 (H-crew) hold w_hh only, compute gh + nonlinearity.
// Weights/thread = 48 VGPRs (vs 96 in the 512-thr design that spilled: R3/R4
// WRITE_SIZE 746MB was scratch traffic from spilling the 96-reg weight array).
__global__ __launch_bounds__(1024, 4)
void gru_fused(const int* __restrict__ inputs, const float* __restrict__ emb,
               const float* __restrict__ w_int, const float* __restrict__ w_ih,
               const float* __restrict__ w_hh, const float* __restrict__ b_ih,
               const float* __restrict__ b_hh, const float* __restrict__ h0,
               float* __restrict__ out) {
  __shared__ unsigned short xs[2][ROWS * NH];  // 32 KB  x tile, bf16, swizzled
  __shared__ unsigned short hs[2][ROWS * NH];  // 32 KB  h tile, bf16, swizzled
  __shared__ unsigned short exch[ROWS * XSTR]; // 49 KB  gi pre-acts, bf16
  __shared__ float gall[NT * ROWS];            // 12.8 KB gates, all timesteps
  __shared__ int idxs[NT * ROWS];              // 12.8 KB token ids

  const int tid = threadIdx.x;
  const int bx = blockIdx.x;
  const int I = bx >> 6;          // interest 0..3
  const int R0 = (bx & 63) * ROWS;
  const int w = tid >> 6;         // wave 0..15
  const int lane = tid & 63;
  const int l15 = lane & 15;
  const int l4 = lane >> 4;
  const int crew = w >> 3;        // 0 = X-crew, 1 = H-crew
  const int cw = w & 7;           // crew-wave: owns h-cols [cw*16, cw*16+16)
  const int col = cw * 16 + l15;

  // X-crew staging mapping: 8 threads per row, 16 floats (64B) each
  const int sr = tid >> 3;  // 0..63 (valid for X-crew tids 0..511)
  const int sp = tid & 7;

  // ---- token indices ----
  for (int e = tid; e < NT * ROWS; e += 1024) {
    int t = e >> 6, r = e & (ROWS - 1);
    idxs[e] = inputs[(size_t)(R0 + r) * NT + t];
  }
  __syncthreads();

  // ---- gate prologue: g[t][r] for all timesteps (coalesced, 16 thr/row) ----
  {
    const int gr = tid >> 4, gs = tid & 15;  // 64 rows x 16 segs = 1024
    float4 wA[NINT], wB[NINT];
    #pragma unroll
    for (int i = 0; i < NINT; ++i) {
      const float4* wv = (const float4*)(w_int + i * NH + gs * 8);
      wA[i] = wv[0];
      wB[i] = wv[1];
    }
    for (int t = 0; t < NT; ++t) {
      int e = t * ROWS + gr;
      const float4* xr = (const float4*)(emb + (size_t)idxs[e] * NH + gs * 8);
      float4 a = xr[0], b = xr[1];
      float d[NINT];
      #pragma unroll
      for (int i = 0; i < NINT; ++i) {
        d[i] = a.x * wA[i].x + a.y * wA[i].y + a.z * wA[i].z + a.w * wA[i].w +
               b.x * wB[i].x + b.y * wB[i].y + b.z * wB[i].z + b.w * wB[i].w;
      }
      #pragma unroll
      for (int off = 1; off < 16; off <<= 1) {
        #pragma unroll
        for (int i = 0; i < NINT; ++i) d[i] += __shfl_xor(d[i], off, 64);
      }
      if (gs == 0) {
        float sa = d[0] * 10.f, sb = d[1] * 10.f, sc = d[2] * 10.f, sd = d[3] * 10.f;
        float mx = fmaxf(fmaxf(sa, sb), fmaxf(sc, sd));
        float ea = __expf(sa - mx), eb = __expf(sb - mx), ec = __expf(sc - mx),
              ed = __expf(sd - mx);
        float sel = (I == 0) ? ea : (I == 1) ? eb : (I == 2) ? ec : ed;
        gall[e] = sel * frcp(ea + eb + ec + ed);
      }
    }
  }

  // ---- per-crew weight fragments (48 VGPRs) + bias ----
  // B-operand of 16x16x32: lane holds col=(lane&15), k = (lane>>4)*8 + 0..7
  const float* wmat = crew ? w_hh : w_ih;
  const float* bvec = crew ? b_hh : b_ih;
  bf16x8 wf[3][4];
  float bias[3];
  #pragma unroll
  for (int g = 0; g < 3; ++g) {
    int oc = g * NH + col;
    bias[g] = bvec[I * 384 + oc];
    #pragma unroll
    for (int kk = 0; kk < 4; ++kk) {
      const float* p = wmat + (size_t)(I * 384 + oc) * NH + kk * 32 + l4 * 8;
      bf16x8 f;
      #pragma unroll
      for (int e = 0; e < 8; ++e) f[e] = (__bf16)p[e];
      wf[g][kk] = f;
    }
  }

  // ---- init: H-crew loads h0 -> hm regs + hs[0]; X-crew stages x(0) ----
  float hm[4][4];  // H-crew only (C/D layout: col=lane&15, row=(lane>>4)*4+j)
  if (crew == 1) {
    #pragma unroll
    for (int m = 0; m < 4; ++m) {
      #pragma unroll
      for (int j = 0; j < 4; ++j) {
        int row = m * 16 + l4 * 4 + j;
        float v = h0[((size_t)I * NB + R0 + row) * NH + col];
        hm[m][j] = v;
        hs[0][(row * NH + col) ^ ((row & 7) << 3)] = bfbits(v);
      }
    }
  } else {
    const float4* src = (const float4*)(emb + (size_t)idxs[sr] * NH + sp * 16);
    float4 v0 = src[0], v1 = src[1], v2 = src[2], v3 = src[3];
    short8 s0, s1;
    s0[0] = bfbits(v0.x); s0[1] = bfbits(v0.y); s0[2] = bfbits(v0.z); s0[3] = bfbits(v0.w);
    s0[4] = bfbits(v1.x); s0[5] = bfbits(v1.y); s0[6] = bfbits(v1.z); s0[7] = bfbits(v1.w);
    s1[0] = bfbits(v2.x); s1[1] = bfbits(v2.y); s1[2] = bfbits(v2.z); s1[3] = bfbits(v2.w);
    s1[4] = bfbits(v3.x); s1[5] = bfbits(v3.y); s1[6] = bfbits(v3.z); s1[7] = bfbits(v3.w);
    int base = sr * NH + sp * 16;
    int sw = (sr & 7) << 3;
    *(short8*)&xs[0][base ^ sw] = s0;
    *(short8*)&xs[0][(base + 8) ^ sw] = s1;
  }
  __syncthreads();

  // ---- main recurrence ----
  for (int t = 0; t < NT; ++t) {
    const int cur = t & 1, nxt = cur ^ 1;
    const bool pf = (t + 1 < NT);
    short8 s0, s1;  // X-crew staged bf16 (4 regs across the barrier)

    if (crew == 0) {
      // issue x(t+1) loads first; latency hides under the gi MFMAs
      float4 v0, v1, v2, v3;
      if (pf) {
        const float4* src =
            (const float4*)(emb + (size_t)idxs[(t + 1) * ROWS + sr] * NH + sp * 16);
        v0 = src[0]; v1 = src[1]; v2 = src[2]; v3 = src[3];
      }
      const unsigned short* xsc = xs[cur];
      #pragma unroll
      for (int m = 0; m < 4; ++m) {
        f32x4 acc[3];
        #pragma unroll
        for (int g = 0; g < 3; ++g) acc[g] = f32x4{bias[g], bias[g], bias[g], bias[g]};
        int arow = m * 16 + l15;
        int alin = arow * NH + l4 * 8;
        int sw2 = (arow & 7) << 3;
        #pragma unroll
        for (int kk = 0; kk < 4; ++kk) {
          int e = (alin + kk * 32) ^ sw2;  // XOR full linear index (carry-free add)
          bf16x8 ax = __builtin_bit_cast(bf16x8, *(const short8*)&xsc[e]);
          #pragma unroll
          for (int g = 0; g < 3; ++g)
            acc[g] = __builtin_amdgcn_mfma_f32_16x16x32_bf16(ax, wf[g][kk], acc[g], 0, 0, 0);
        }
        #pragma unroll
        for (int g = 0; g < 3; ++g)
          #pragma unroll
          for (int j = 0; j < 4; ++j)
            exch[(m * 16 + l4 * 4 + j) * XSTR + g * NH + col] = bfbits(acc[g][j]);
      }
      if (pf) {
        s0[0] = bfbits(v0.x); s0[1] = bfbits(v0.y); s0[2] = bfbits(v0.z); s0[3] = bfbits(v0.w);
        s0[4] = bfbits(v1.x); s0[5] = bfbits(v1.y); s0[6] = bfbits(v1.z); s0[7] = bfbits(v1.w);
        s1[0] = bfbits(v2.x); s1[1] = bfbits(v2.y); s1[2] = bfbits(v2.z); s1[3] = bfbits(v2.w);
        s1[4] = bfbits(v3.x); s1[5] = bfbits(v3.y); s1[6] = bfbits(v3.z); s1[7] = bfbits(v3.w);
      }
    }
    __syncthreads();  // exch ready; hs[cur]/xs[cur] fully consumed? (X done w/ xs)

    if (crew == 0) {
      if (pf) {
        int base = sr * NH + sp * 16;
        int sw = (sr & 7) << 3;
        *(short8*)&xs[nxt][base ^ sw] = s0;
        *(short8*)&xs[nxt][(base + 8) ^ sw] = s1;
      }
    } else {
      const unsigned short* hsc = hs[cur];
      unsigned short* hsn = hs[nxt];
      #pragma unroll
      for (int m = 0; m < 4; ++m) {
        f32x4 acc[3];
        #pragma unroll
        for (int g = 0; g < 3; ++g) acc[g] = f32x4{bias[g], bias[g], bias[g], bias[g]};
        int arow = m * 16 + l15;
        int alin = arow * NH + l4 * 8;
        int sw2 = (arow & 7) << 3;
        #pragma unroll
        for (int kk = 0; kk < 4; ++kk) {
          int e = (alin + kk * 32) ^ sw2;
          bf16x8 ah = __builtin_bit_cast(bf16x8, *(const short8*)&hsc[e]);
          #pragma unroll
          for (int g = 0; g < 3; ++g)
            acc[g] = __builtin_amdgcn_mfma_f32_16x16x32_bf16(ah, wf[g][kk], acc[g], 0, 0, 0);
        }
        #pragma unroll
        for (int j = 0; j < 4; ++j) {
          int row = m * 16 + l4 * 4 + j;
          float gi_r = bf2f(exch[row * XSTR + 0 * NH + col]);
          float gi_i = bf2f(exch[row * XSTR + 1 * NH + col]);
          float gi_n = bf2f(exch[row * XSTR + 2 * NH + col]);
          float rg = sigm(gi_r + acc[0][j]);
          float ig = sigm(gi_i + acc[1][j]);
          float ng = tanh_(gi_n + rg * acc[2][j]);
          float gv = gall[t * ROWS + row];
          float c = (gv > 0.01f) ? gv * ig : 0.0f;
          float hy = hm[m][j] + c * (ng - hm[m][j]);
          hm[m][j] = hy;
          hsn[(row * NH + col) ^ ((row & 7) << 3)] = bfbits(hy);
        }
      }
    }
    __syncthreads();  // hs[nxt]/xs[nxt] complete; exch free for overwrite
  }

  // ---- epilogue: H-crew writes out[b][I][h] ----
  if (crew == 1) {
    #pragma unroll
    for (int m = 0; m < 4; ++m) {
      #pragma unroll
      for (int j = 0; j < 4; ++j) {
        int row = m * 16 + l4 * 4 + j;
        out[(size_t)(R0 + row) * (NINT * NH) + I * NH + col] = hm[m][j];
      }
    }
  }
}

extern "C" void kernel_launch(void* const* d_in, const int* in_sizes, int n_in,
                              void* d_out, int out_size, void* d_ws, size_t ws_size,
                              hipStream_t stream) {
  const int* inputs = (const int*)d_in[0];
  const float* emb = (const float*)d_in[1];
  const float* w_int = (const float*)d_in[2];
  const float* w_ih = (const float*)d_in[3];
  const float* w_hh = (const float*)d_in[4];
  const float* b_ih = (const float*)d_in[5];
  const float* b_hh = (const float*)d_in[6];
  const float* h0 = (const float*)d_in[7];
  float* out = (float*)d_out;

  dim3 grid(NINT * (NB / ROWS));  // 256 blocks, one per CU
  dim3 block(1024);
  gru_fused<<<grid, block, 0, stream>>>(inputs, emb, w_int, w_ih, w_hh, b_ih,
                                        b_hh, h0, out);
}

// Round 6
// 244.294 us; speedup vs baseline: 4.8315x; 3.1109x over previous
//
#include <hip/hip_runtime.h>
#include <hip/hip_bf16.h>

#define NB 4096
#define NT 50
#define NH 128
#define NINT 4
#define ROWS 64  // batch rows per block

typedef float f32x4 __attribute__((ext_vector_type(4)));
typedef __bf16 bf16x8 __attribute__((ext_vector_type(8)));
typedef short short8 __attribute__((ext_vector_type(8)));

__device__ __forceinline__ float frcp(float x) { return __builtin_amdgcn_rcpf(x); }

__device__ __forceinline__ unsigned short bfbits(float f) {
  __bf16 b = (__bf16)f;  // native RTNE; pairs pack to v_cvt_pk_bf16_f32
  return __builtin_bit_cast(unsigned short, b);
}
__device__ __forceinline__ float sigm(float x) { return frcp(1.0f + __expf(-x)); }
__device__ __forceinline__ float tanh_(float x) {
  return 2.0f * frcp(1.0f + __expf(-2.0f * x)) - 1.0f;
}

// Grid: 256 blocks = NINT(4) * (NB/64).  Block: 512 threads = 8 waves, 1/CU.
// REGISTER BUDGET IS THE DESIGN CONSTRAINT (R3-R5 lesson): the 96-reg/thread
// persistent weight set only fits under __launch_bounds__(512,2) -> 256-reg
// unified budget.  Any min-waves/EU=4 bound caps at 128 and the compiler's
// even VGPR/AGPR split (64/64) spills the weights to scratch (R5: WRITE_SIZE
// 250MB, VGPR_Count=64, 760us).  R2 with this skeleton measured VGPR=128,
// WRITE 25MB, no spill.
__global__ __launch_bounds__(512, 2)
void gru_fused(const int* __restrict__ inputs, const float* __restrict__ emb,
               const float* __restrict__ w_int, const float* __restrict__ w_ih,
               const float* __restrict__ w_hh, const float* __restrict__ b_ih,
               const float* __restrict__ b_hh, const float* __restrict__ h0,
               float* __restrict__ out) {
  __shared__ unsigned short xs[2][ROWS * NH];  // 32 KB x tile, bf16, swizzled
  __shared__ unsigned short hs[2][ROWS * NH];  // 32 KB h tile, bf16, swizzled
  __shared__ float gall[NT * ROWS];            // 12.8 KB gates, all timesteps
  __shared__ int idxs[NT * ROWS];              // 12.8 KB token ids

  const int tid = threadIdx.x;
  const int bx = blockIdx.x;
  const int I = bx >> 6;          // interest 0..3
  const int R0 = (bx & 63) * ROWS;
  const int w = tid >> 6;         // wave 0..7
  const int lane = tid & 63;
  const int l15 = lane & 15;
  const int l4 = lane >> 4;
  const int col = w * 16 + l15;   // this lane's output column (0..127)

  // staging/gather mapping: 8 threads per row, 16 floats (64B) each
  const int sr = tid >> 3;  // row 0..63
  const int sp = tid & 7;   // segment

  // ---- token indices ----
  for (int e = tid; e < NT * ROWS; e += 512) {
    int t = e >> 6, r = e & (ROWS - 1);
    idxs[e] = inputs[(size_t)(R0 + r) * NT + t];
  }
  __syncthreads();

  // ---- gate prologue: g[t][r] for ALL timesteps (coalesced, 8 thr/row) ----
  {
    float4 wv[NINT][4];
    #pragma unroll
    for (int i = 0; i < NINT; ++i) {
      const float4* p = (const float4*)(w_int + i * NH + sp * 16);
      #pragma unroll
      for (int q = 0; q < 4; ++q) wv[i][q] = p[q];
    }
    for (int t = 0; t < NT; ++t) {
      int e = t * ROWS + sr;
      const float4* xr = (const float4*)(emb + (size_t)idxs[e] * NH + sp * 16);
      float4 a = xr[0], b = xr[1], c = xr[2], dd = xr[3];
      float d[NINT];
      #pragma unroll
      for (int i = 0; i < NINT; ++i) {
        d[i] = a.x * wv[i][0].x + a.y * wv[i][0].y + a.z * wv[i][0].z + a.w * wv[i][0].w +
               b.x * wv[i][1].x + b.y * wv[i][1].y + b.z * wv[i][1].z + b.w * wv[i][1].w +
               c.x * wv[i][2].x + c.y * wv[i][2].y + c.z * wv[i][2].z + c.w * wv[i][2].w +
               dd.x * wv[i][3].x + dd.y * wv[i][3].y + dd.z * wv[i][3].z + dd.w * wv[i][3].w;
      }
      #pragma unroll
      for (int off = 1; off < 8; off <<= 1) {
        #pragma unroll
        for (int i = 0; i < NINT; ++i) d[i] += __shfl_xor(d[i], off, 64);
      }
      if (sp == 0) {
        float sa = d[0] * 10.f, sb = d[1] * 10.f, sc = d[2] * 10.f, sd = d[3] * 10.f;
        float mx = fmaxf(fmaxf(sa, sb), fmaxf(sc, sd));
        float ea = __expf(sa - mx), eb = __expf(sb - mx), ec = __expf(sc - mx),
              ed = __expf(sd - mx);
        float sel = (I == 0) ? ea : (I == 1) ? eb : (I == 2) ? ec : ed;
        gall[e] = sel * frcp(ea + eb + ec + ed);
      }
    }
  }

  // ---- persistent weight fragments in registers (96 VGPR) + biases ----
  // B-operand of 16x16x32: lane holds col=(lane&15), k = (lane>>4)*8 + 0..7
  bf16x8 wih[3][4], whh[3][4];
  float bih[3], bhh[3];
  #pragma unroll
  for (int g = 0; g < 3; ++g) {
    int oc = g * NH + col;
    bih[g] = b_ih[I * 384 + oc];
    bhh[g] = b_hh[I * 384 + oc];
    #pragma unroll
    for (int kk = 0; kk < 4; ++kk) {
      int k0 = kk * 32 + l4 * 8;
      const float* pi = w_ih + ((size_t)(I * 384 + oc) * NH + k0);
      const float* ph = w_hh + ((size_t)(I * 384 + oc) * NH + k0);
      bf16x8 si, sh;
      #pragma unroll
      for (int e = 0; e < 8; ++e) {
        si[e] = (__bf16)pi[e];
        sh[e] = (__bf16)ph[e];
      }
      wih[g][kk] = si;
      whh[g][kk] = sh;
    }
  }

  // ---- h0 master (fp32 regs) + initial bf16 LDS copy ----
  // C/D layout: col = lane&15, row = (lane>>4)*4 + reg
  float hm[4][4];
  #pragma unroll
  for (int m = 0; m < 4; ++m) {
    #pragma unroll
    for (int j = 0; j < 4; ++j) {
      int row = m * 16 + l4 * 4 + j;
      float v = h0[((size_t)I * NB + R0 + row) * NH + col];
      hm[m][j] = v;
      hs[0][(row * NH + col) ^ ((row & 7) << 3)] = bfbits(v);
    }
  }

  // ---- stage x(0) ----
  {
    const float4* src = (const float4*)(emb + (size_t)idxs[sr] * NH + sp * 16);
    float4 v0 = src[0], v1 = src[1], v2 = src[2], v3 = src[3];
    short8 s0, s1;
    s0[0] = bfbits(v0.x); s0[1] = bfbits(v0.y); s0[2] = bfbits(v0.z); s0[3] = bfbits(v0.w);
    s0[4] = bfbits(v1.x); s0[5] = bfbits(v1.y); s0[6] = bfbits(v1.z); s0[7] = bfbits(v1.w);
    s1[0] = bfbits(v2.x); s1[1] = bfbits(v2.y); s1[2] = bfbits(v2.z); s1[3] = bfbits(v2.w);
    s1[4] = bfbits(v3.x); s1[5] = bfbits(v3.y); s1[6] = bfbits(v3.z); s1[7] = bfbits(v3.w);
    int base = sr * NH + sp * 16;
    int sw = (sr & 7) << 3;
    *(short8*)&xs[0][base ^ sw] = s0;
    *(short8*)&xs[0][(base + 8) ^ sw] = s1;
  }
  __syncthreads();

  // ---- main recurrence ----
  for (int t = 0; t < NT; ++t) {
    const int cur = t & 1, nxt = cur ^ 1;
    const bool pf = (t + 1 < NT);

    // prefetch x(t+1) into regs; latency hides under the 96 MFMAs
    float4 v0, v1, v2, v3;
    if (pf) {
      const float4* src =
          (const float4*)(emb + (size_t)idxs[(t + 1) * ROWS + sr] * NH + sp * 16);
      v0 = src[0]; v1 = src[1]; v2 = src[2]; v3 = src[3];
    }

    const unsigned short* hsc = hs[cur];
    const unsigned short* xsc = xs[cur];
    unsigned short* hsn = hs[nxt];

    #pragma unroll
    for (int m = 0; m < 4; ++m) {
      f32x4 agi[3], agh[3];
      #pragma unroll
      for (int g = 0; g < 3; ++g) {
        agi[g] = f32x4{bih[g], bih[g], bih[g], bih[g]};
        agh[g] = f32x4{bhh[g], bhh[g], bhh[g], bhh[g]};
      }
      int arow = m * 16 + l15;
      int alin = arow * NH + l4 * 8;  // bits 3-4
      int sw2 = (arow & 7) << 3;      // bits 3-5
      #pragma unroll
      for (int kk = 0; kk < 4; ++kk) {
        int e = (alin + kk * 32) ^ sw2;  // kk*32: bits 5-6, carry-free; XOR full index
        bf16x8 ah = __builtin_bit_cast(bf16x8, *(const short8*)&hsc[e]);
        bf16x8 ax = __builtin_bit_cast(bf16x8, *(const short8*)&xsc[e]);
        #pragma unroll
        for (int g = 0; g < 3; ++g) {
          agh[g] = __builtin_amdgcn_mfma_f32_16x16x32_bf16(ah, whh[g][kk], agh[g], 0, 0, 0);
          agi[g] = __builtin_amdgcn_mfma_f32_16x16x32_bf16(ax, wih[g][kk], agi[g], 0, 0, 0);
        }
      }
      #pragma unroll
      for (int j = 0; j < 4; ++j) {
        int row = m * 16 + l4 * 4 + j;
        float gv = gall[t * ROWS + row];
        float rg = sigm(agi[0][j] + agh[0][j]);
        float ig = sigm(agi[1][j] + agh[1][j]);
        float ng = tanh_(agi[2][j] + rg * agh[2][j]);
        float c = (gv > 0.01f) ? gv * ig : 0.0f;
        float hy = hm[m][j] + c * (ng - hm[m][j]);
        hm[m][j] = hy;
        hsn[(row * NH + col) ^ ((row & 7) << 3)] = bfbits(hy);
      }
    }

    if (pf) {
      short8 s0, s1;
      s0[0] = bfbits(v0.x); s0[1] = bfbits(v0.y); s0[2] = bfbits(v0.z); s0[3] = bfbits(v0.w);
      s0[4] = bfbits(v1.x); s0[5] = bfbits(v1.y); s0[6] = bfbits(v1.z); s0[7] = bfbits(v1.w);
      s1[0] = bfbits(v2.x); s1[1] = bfbits(v2.y); s1[2] = bfbits(v2.z); s1[3] = bfbits(v2.w);
      s1[4] = bfbits(v3.x); s1[5] = bfbits(v3.y); s1[6] = bfbits(v3.z); s1[7] = bfbits(v3.w);
      int base = sr * NH + sp * 16;
      int sw = (sr & 7) << 3;
      *(short8*)&xs[nxt][base ^ sw] = s0;
      *(short8*)&xs[nxt][(base + 8) ^ sw] = s1;
    }
    __syncthreads();
  }

  // ---- epilogue: out[b][I][h] ----
  #pragma unroll
  for (int m = 0; m < 4; ++m) {
    #pragma unroll
    for (int j = 0; j < 4; ++j) {
      int row = m * 16 + l4 * 4 + j;
      out[(size_t)(R0 + row) * (NINT * NH) + I * NH + col] = hm[m][j];
    }
  }
}

extern "C" void kernel_launch(void* const* d_in, const int* in_sizes, int n_in,
                              void* d_out, int out_size, void* d_ws, size_t ws_size,
                              hipStream_t stream) {
  const int* inputs = (const int*)d_in[0];
  const float* emb = (const float*)d_in[1];
  const float* w_int = (const float*)d_in[2];
  const float* w_ih = (const float*)d_in[3];
  const float* w_hh = (const float*)d_in[4];
  const float* b_ih = (const float*)d_in[5];
  const float* b_hh = (const float*)d_in[6];
  const float* h0 = (const float*)d_in[7];
  float* out = (float*)d_out;

  dim3 grid(NINT * (NB / ROWS));  // 256 blocks, one per CU
  dim3 block(512);
  gru_fused<<<grid, block, 0, stream>>>(inputs, emb, w_int, w_ih, w_hh, b_ih,
                                        b_hh, h0, out);
}

// Round 7
// 202.115 us; speedup vs baseline: 5.8398x; 1.2087x over previous
//
#include <hip/hip_runtime.h>
#include <hip/hip_bf16.h>

#define NB 4096
#define NT 50
#define NH 128
#define NINT 4
#define ROWS 64  // batch rows per block

typedef float f32x4 __attribute__((ext_vector_type(4)));
typedef __bf16 bf16x8 __attribute__((ext_vector_type(8)));
typedef short short8 __attribute__((ext_vector_type(8)));

#define L2E 1.4426950408889634f

__device__ __forceinline__ float frcp(float x) { return __builtin_amdgcn_rcpf(x); }

// exp2(-x) in one instruction: v_exp_f32 computes 2^x; neg is a free src modifier.
__device__ __forceinline__ float exp2neg(float x) {
  float r;
  asm("v_exp_f32 %0, -%1" : "=v"(r) : "v"(x));
  return r;
}

__device__ __forceinline__ unsigned short bfbits(float f) {
  __bf16 b = (__bf16)f;  // native RTNE; pairs pack to v_cvt_pk_bf16_f32
  return __builtin_bit_cast(unsigned short, b);
}

// Grid: 256 blocks = NINT(4) * (NB/64).  Block: 512 threads = 8 waves, 1/CU.
// REGISTER BUDGET IS THE DESIGN CONSTRAINT (R3-R5 lesson): the 96-reg/thread
// persistent weight set only fits under __launch_bounds__(512,2) -> 256-reg
// unified budget.  Any min-waves/EU=4 bound caps at 128 and the compiler's
// even VGPR/AGPR split (64/64) spills the weights to scratch (R5: WRITE_SIZE
// 250MB, VGPR_Count=64, 760us).  R6 measured: VGPR=128, no spill, 244us.
//
// R7 changes (VALU diet; R6 counters: VALUBusy 47% = top pipe, ~1375 VALU
// instr/wave/step in the serial loop):
//  - weights/biases pre-scaled by log2e (gates r,i) and 2*log2e (gate n):
//    MFMA output is directly the v_exp_f32 argument; sigmoid = rcp(1+exp2(-a))
//  - gh MFMAs chain into the gi accumulator for gates r,i (C in = C out):
//    4 accs/m instead of 6, no post-adds
//  - gall pre-thresholded in prologue; float4-read per m (4 reads vs 16)
//  - s_setprio(1) around the MFMA cluster
__global__ __launch_bounds__(512, 2)
void gru_fused(const int* __restrict__ inputs, const float* __restrict__ emb,
               const float* __restrict__ w_int, const float* __restrict__ w_ih,
               const float* __restrict__ w_hh, const float* __restrict__ b_ih,
               const float* __restrict__ b_hh, const float* __restrict__ h0,
               float* __restrict__ out) {
  __shared__ unsigned short xs[2][ROWS * NH];   // 32 KB x tile, bf16, swizzled
  __shared__ unsigned short hs[2][ROWS * NH];   // 32 KB h tile, bf16, swizzled
  __shared__ __align__(16) float gall[NT * ROWS];  // 12.8 KB pre-thresholded gates
  __shared__ int idxs[NT * ROWS];               // 12.8 KB token ids

  const int tid = threadIdx.x;
  const int bx = blockIdx.x;
  const int I = bx >> 6;          // interest 0..3
  const int R0 = (bx & 63) * ROWS;
  const int w = tid >> 6;         // wave 0..7
  const int lane = tid & 63;
  const int l15 = lane & 15;
  const int l4 = lane >> 4;
  const int col = w * 16 + l15;   // this lane's output column (0..127)

  // staging/gather mapping: 8 threads per row, 16 floats (64B) each
  const int sr = tid >> 3;  // row 0..63
  const int sp = tid & 7;   // segment

  // ---- token indices ----
  for (int e = tid; e < NT * ROWS; e += 512) {
    int t = e >> 6, r = e & (ROWS - 1);
    idxs[e] = inputs[(size_t)(R0 + r) * NT + t];
  }
  __syncthreads();

  // ---- gate prologue: g[t][r] for ALL timesteps (coalesced, 8 thr/row),
  //      stored PRE-THRESHOLDED: (g>0.01 ? g : 0) ----
  {
    float4 wv[NINT][4];
    #pragma unroll
    for (int i = 0; i < NINT; ++i) {
      const float4* p = (const float4*)(w_int + i * NH + sp * 16);
      #pragma unroll
      for (int q = 0; q < 4; ++q) wv[i][q] = p[q];
    }
    for (int t = 0; t < NT; ++t) {
      int e = t * ROWS + sr;
      const float4* xr = (const float4*)(emb + (size_t)idxs[e] * NH + sp * 16);
      float4 a = xr[0], b = xr[1], c = xr[2], dd = xr[3];
      float d[NINT];
      #pragma unroll
      for (int i = 0; i < NINT; ++i) {
        d[i] = a.x * wv[i][0].x + a.y * wv[i][0].y + a.z * wv[i][0].z + a.w * wv[i][0].w +
               b.x * wv[i][1].x + b.y * wv[i][1].y + b.z * wv[i][1].z + b.w * wv[i][1].w +
               c.x * wv[i][2].x + c.y * wv[i][2].y + c.z * wv[i][2].z + c.w * wv[i][2].w +
               dd.x * wv[i][3].x + dd.y * wv[i][3].y + dd.z * wv[i][3].z + dd.w * wv[i][3].w;
      }
      #pragma unroll
      for (int off = 1; off < 8; off <<= 1) {
        #pragma unroll
        for (int i = 0; i < NINT; ++i) d[i] += __shfl_xor(d[i], off, 64);
      }
      if (sp == 0) {
        float sa = d[0] * 10.f, sb = d[1] * 10.f, sc = d[2] * 10.f, sd = d[3] * 10.f;
        float mx = fmaxf(fmaxf(sa, sb), fmaxf(sc, sd));
        float ea = __expf(sa - mx), eb = __expf(sb - mx), ec = __expf(sc - mx),
              ed = __expf(sd - mx);
        float sel = (I == 0) ? ea : (I == 1) ? eb : (I == 2) ? ec : ed;
        float gv = sel * frcp(ea + eb + ec + ed);
        gall[e] = (gv > 0.01f) ? gv : 0.0f;
      }
    }
  }

  // ---- persistent weight fragments in registers (96 VGPR) + biases,
  //      PRE-SCALED so the MFMA result is the exp2 argument:
  //      gates r,i: *log2e   gate n: *2*log2e ----
  // B-operand of 16x16x32: lane holds col=(lane&15), k = (lane>>4)*8 + 0..7
  bf16x8 wih[3][4], whh[3][4];
  float biasRI[2];  // (b_ih+b_hh)*log2e for gates r,i (fused accumulator init)
  float biasNI, biasNH;
  {
    const float gs[3] = {L2E, L2E, 2.0f * L2E};
    #pragma unroll
    for (int g = 0; g < 3; ++g) {
      int oc = g * NH + col;
      #pragma unroll
      for (int kk = 0; kk < 4; ++kk) {
        int k0 = kk * 32 + l4 * 8;
        const float* pi = w_ih + ((size_t)(I * 384 + oc) * NH + k0);
        const float* ph = w_hh + ((size_t)(I * 384 + oc) * NH + k0);
        bf16x8 si, sh;
        #pragma unroll
        for (int e = 0; e < 8; ++e) {
          si[e] = (__bf16)(pi[e] * gs[g]);
          sh[e] = (__bf16)(ph[e] * gs[g]);
        }
        wih[g][kk] = si;
        whh[g][kk] = sh;
      }
    }
    biasRI[0] = (b_ih[I * 384 + col] + b_hh[I * 384 + col]) * L2E;
    biasRI[1] = (b_ih[I * 384 + NH + col] + b_hh[I * 384 + NH + col]) * L2E;
    biasNI = b_ih[I * 384 + 2 * NH + col] * (2.0f * L2E);
    biasNH = b_hh[I * 384 + 2 * NH + col] * (2.0f * L2E);
  }

  // ---- h0 master (fp32 regs) + initial bf16 LDS copy ----
  // C/D layout: col = lane&15, row = (lane>>4)*4 + reg
  float hm[4][4];
  #pragma unroll
  for (int m = 0; m < 4; ++m) {
    #pragma unroll
    for (int j = 0; j < 4; ++j) {
      int row = m * 16 + l4 * 4 + j;
      float v = h0[((size_t)I * NB + R0 + row) * NH + col];
      hm[m][j] = v;
      hs[0][(row * NH + col) ^ ((row & 7) << 3)] = bfbits(v);
    }
  }

  // ---- stage x(0) ----
  {
    const float4* src = (const float4*)(emb + (size_t)idxs[sr] * NH + sp * 16);
    float4 v0 = src[0], v1 = src[1], v2 = src[2], v3 = src[3];
    short8 s0, s1;
    s0[0] = bfbits(v0.x); s0[1] = bfbits(v0.y); s0[2] = bfbits(v0.z); s0[3] = bfbits(v0.w);
    s0[4] = bfbits(v1.x); s0[5] = bfbits(v1.y); s0[6] = bfbits(v1.z); s0[7] = bfbits(v1.w);
    s1[0] = bfbits(v2.x); s1[1] = bfbits(v2.y); s1[2] = bfbits(v2.z); s1[3] = bfbits(v2.w);
    s1[4] = bfbits(v3.x); s1[5] = bfbits(v3.y); s1[6] = bfbits(v3.z); s1[7] = bfbits(v3.w);
    int base = sr * NH + sp * 16;
    int sw = (sr & 7) << 3;
    *(short8*)&xs[0][base ^ sw] = s0;
    *(short8*)&xs[0][(base + 8) ^ sw] = s1;
  }
  __syncthreads();

  // ---- main recurrence ----
  for (int t = 0; t < NT; ++t) {
    const int cur = t & 1, nxt = cur ^ 1;
    const bool pf = (t + 1 < NT);

    // prefetch x(t+1) into regs; latency hides under the 96 MFMAs
    float4 v0, v1, v2, v3;
    if (pf) {
      const float4* src =
          (const float4*)(emb + (size_t)idxs[(t + 1) * ROWS + sr] * NH + sp * 16);
      v0 = src[0]; v1 = src[1]; v2 = src[2]; v3 = src[3];
    }

    const unsigned short* hsc = hs[cur];
    const unsigned short* xsc = xs[cur];
    unsigned short* hsn = hs[nxt];

    #pragma unroll
    for (int m = 0; m < 4; ++m) {
      // fused accumulators: aR/aI hold gi+gh (+both biases); aNI/aNH separate
      f32x4 aR = f32x4{biasRI[0], biasRI[0], biasRI[0], biasRI[0]};
      f32x4 aI = f32x4{biasRI[1], biasRI[1], biasRI[1], biasRI[1]};
      f32x4 aNI = f32x4{biasNI, biasNI, biasNI, biasNI};
      f32x4 aNH = f32x4{biasNH, biasNH, biasNH, biasNH};

      int arow = m * 16 + l15;
      int alin = arow * NH + l4 * 8;  // bits 3-4
      int sw2 = (arow & 7) << 3;      // bits 3-5
      __builtin_amdgcn_s_setprio(1);
      #pragma unroll
      for (int kk = 0; kk < 4; ++kk) {
        int e = (alin + kk * 32) ^ sw2;  // kk*32: bits 5-6, carry-free; XOR full index
        bf16x8 ah = __builtin_bit_cast(bf16x8, *(const short8*)&hsc[e]);
        bf16x8 ax = __builtin_bit_cast(bf16x8, *(const short8*)&xsc[e]);
        aR = __builtin_amdgcn_mfma_f32_16x16x32_bf16(ax, wih[0][kk], aR, 0, 0, 0);
        aR = __builtin_amdgcn_mfma_f32_16x16x32_bf16(ah, whh[0][kk], aR, 0, 0, 0);
        aI = __builtin_amdgcn_mfma_f32_16x16x32_bf16(ax, wih[1][kk], aI, 0, 0, 0);
        aI = __builtin_amdgcn_mfma_f32_16x16x32_bf16(ah, whh[1][kk], aI, 0, 0, 0);
        aNI = __builtin_amdgcn_mfma_f32_16x16x32_bf16(ax, wih[2][kk], aNI, 0, 0, 0);
        aNH = __builtin_amdgcn_mfma_f32_16x16x32_bf16(ah, whh[2][kk], aNH, 0, 0, 0);
      }
      __builtin_amdgcn_s_setprio(0);

      const f32x4 gq = *(const f32x4*)&gall[t * ROWS + m * 16 + l4 * 4];
      #pragma unroll
      for (int j = 0; j < 4; ++j) {
        int row = m * 16 + l4 * 4 + j;
        float rg = frcp(1.0f + exp2neg(aR[j]));          // sigm, pre-scaled arg
        float ig = frcp(1.0f + exp2neg(aI[j]));
        float an = fmaf(rg, aNH[j], aNI[j]);             // 2*log2e*(i_n + r*h_n)
        float ng = fmaf(2.0f, frcp(1.0f + exp2neg(an)), -1.0f);  // tanh
        float c = gq[j] * ig;                            // gall pre-thresholded
        float hy = fmaf(c, ng - hm[m][j], hm[m][j]);
        hm[m][j] = hy;
        hsn[(row * NH + col) ^ ((row & 7) << 3)] = bfbits(hy);
      }
    }

    if (pf) {
      short8 s0, s1;
      s0[0] = bfbits(v0.x); s0[1] = bfbits(v0.y); s0[2] = bfbits(v0.z); s0[3] = bfbits(v0.w);
      s0[4] = bfbits(v1.x); s0[5] = bfbits(v1.y); s0[6] = bfbits(v1.z); s0[7] = bfbits(v1.w);
      s1[0] = bfbits(v2.x); s1[1] = bfbits(v2.y); s1[2] = bfbits(v2.z); s1[3] = bfbits(v2.w);
      s1[4] = bfbits(v3.x); s1[5] = bfbits(v3.y); s1[6] = bfbits(v3.z); s1[7] = bfbits(v3.w);
      int base = sr * NH + sp * 16;
      int sw = (sr & 7) << 3;
      *(short8*)&xs[nxt][base ^ sw] = s0;
      *(short8*)&xs[nxt][(base + 8) ^ sw] = s1;
    }
    __syncthreads();
  }

  // ---- epilogue: out[b][I][h] ----
  #pragma unroll
  for (int m = 0; m < 4; ++m) {
    #pragma unroll
    for (int j = 0; j < 4; ++j) {
      int row = m * 16 + l4 * 4 + j;
      out[(size_t)(R0 + row) * (NINT * NH) + I * NH + col] = hm[m][j];
    }
  }
}

extern "C" void kernel_launch(void* const* d_in, const int* in_sizes, int n_in,
                              void* d_out, int out_size, void* d_ws, size_t ws_size,
                              hipStream_t stream) {
  const int* inputs = (const int*)d_in[0];
  const float* emb = (const float*)d_in[1];
  const float* w_int = (const float*)d_in[2];
  const float* w_ih = (const float*)d_in[3];
  const float* w_hh = (const float*)d_in[4];
  const float* b_ih = (const float*)d_in[5];
  const float* b_hh = (const float*)d_in[6];
  const float* h0 = (const float*)d_in[7];
  float* out = (float*)d_out;

  dim3 grid(NINT * (NB / ROWS));  // 256 blocks, one per CU
  dim3 block(512);
  gru_fused<<<grid, block, 0, stream>>>(inputs, emb, w_int, w_ih, w_hh, b_ih,
                                        b_hh, h0, out);
}